// Round 11
// baseline (324.276 us; speedup 1.0000x reference)
//
#include <hip/hip_runtime.h>

#define T_DIM 512
#define C_DIM 48
#define BPS   48          // bp row stride; 16-lane spill into next row is benign (see store)
#define CH    4           // global-prefetch chunk
#define SPAD  50          // pre-pass scratch row stride (floats); 8B-aligned rows

#if __has_builtin(__builtin_amdgcn_readlane)
#define READLANE_I(v, l) __builtin_amdgcn_readlane((v), (l))
#else
#define READLANE_I(v, l) __shfl((v), (l), 64)
#endif

// Compiler-level ordering fence for single-wave LDS communication.
#if __has_builtin(__builtin_amdgcn_wave_barrier)
#define WAVE_SYNC() do { __asm__ __volatile__("" ::: "memory"); __builtin_amdgcn_wave_barrier(); } while (0)
#else
#define WAVE_SYNC() __asm__ __volatile__("" ::: "memory")
#endif

__device__ __forceinline__ unsigned umin_(unsigned a, unsigned b) { return a < b ? a : b; }
__device__ __forceinline__ float rlane_f(float x, int lane) {
    return __int_as_float(READLANE_I(__float_as_int(x), lane));
}
__device__ __forceinline__ float max3f(float a, float b, float c) {
    float d;
    asm("v_max3_f32 %0, %1, %2, %3" : "=v"(d) : "v"(a), "v"(b), "v"(c));
    return d;
}
__device__ __forceinline__ unsigned min3u(unsigned a, unsigned b, unsigned c) {
    unsigned d;
    asm("v_min3_u32 %0, %1, %2, %3" : "=v"(d) : "v"(a), "v"(b), "v"(c));
    return d;
}

// DPP wave-max (only used once, for tmax). Lanes keep own value on invalid src.
#define DPP_MAX_STEP(V_, CTRL_) do {                                          \
    int o_ = __builtin_amdgcn_update_dpp(__float_as_int(V_),                  \
                                         __float_as_int(V_),                  \
                                         (CTRL_), 0xF, 0xF, false);           \
    V_ = fmaxf(V_, __int_as_float(o_));                                       \
} while (0)
__device__ __forceinline__ float wave_max_f(float v) {
    DPP_MAX_STEP(v, 0x111);
    DPP_MAX_STEP(v, 0x112);
    DPP_MAX_STEP(v, 0x114);
    DPP_MAX_STEP(v, 0x118);
    DPP_MAX_STEP(v, 0x142);
    DPP_MAX_STEP(v, 0x143);
    return __int_as_float(READLANE_I(__float_as_int(v), 63));
}

__global__ __launch_bounds__(64) void crf_viterbi(
    const float* __restrict__ pot,     // [B][T][C]
    const int*   __restrict__ seqlen,  // [B][1]
    const float* __restrict__ trans,   // [C][C]
    float*       __restrict__ out)     // [B][T][C] one-hot f32
{
    const int b   = blockIdx.x;
    const int tid = threadIdx.x;
    const int jj  = (tid < C_DIM) ? tid : (C_DIM - 1);  // clamped for safe loads

    __shared__ __align__(16) float trl[C_DIM * C_DIM];   // transitions, row-major
    __shared__ __align__(16) unsigned char bp[T_DIM * BPS]; // forward bp; pre-pass scratch alias
    __shared__ __align__(4) unsigned char tags[T_DIM];
    __shared__ __align__(16) float fsc[64];              // final scores
    __shared__ unsigned candA[T_DIM];                    // c0..c3 (6b each) | cnt<<28
    __shared__ unsigned candB[T_DIM];                    // c4..c7 (6b each)

    const float* potb = pot + (size_t)b * (T_DIM * C_DIM);
    const int L   = seqlen[b];          // in [1, 511]
    const int thi = L - 1;

    // ---- stage transitions into LDS (coalesced) + tmax = max|Tr| ----
    float tm = 0.0f;
    for (int i = tid; i < C_DIM * C_DIM; i += 64) {      // 36 iters exactly
        float v = trans[i];
        trl[i] = v;
        tm = fmaxf(tm, fabsf(v));
    }
    const float tmax = wave_max_f(tm);                   // uniform
    const float nC5 = -(5.0f * tmax + 1e-3f);            // candidate window
    WAVE_SYNC();

    // ==== PRE-PASS: candidate sets for ALL steps (input-only, data-parallel) ====
    // Candidates for step t are {i : pot[t-1][i] >= rowmax(t-1) + nC5} (R10-proven
    // superset of possible winners; fp slack >> rounding at O(5) magnitudes).
    // Lane l owns row t0+l per 64-row tile; rows staged coalesced via LDS scratch.
    {
        float* scratch = (float*)bp;                     // 64*SPAD*4 = 12.8KB <= 24.5KB
        for (int tile = 0; tile < T_DIM / 64; ++tile) {
            const int t0 = tile * 64;
            const float4* gp4 = (const float4*)(potb + t0 * C_DIM);
#pragma unroll
            for (int it = 0; it < 12; ++it) {            // 768 float4, coalesced
                const int i4  = tid + it * 64;
                const float4 g = gp4[i4];
                const int row = i4 / 12;
                const int e4  = (i4 - row * 12) * 4;
                float* d = &scratch[row * SPAD + e4];
                d[0] = g.x; d[1] = g.y; d[2] = g.z; d[3] = g.w;
            }
            WAVE_SYNC();
            const float2* r2 = (const float2*)&scratch[tid * SPAD];
            // pass 1: exact row max (fp max is order-independent -> bit-exact)
            float rmax = -__builtin_huge_valf();
#pragma unroll
            for (int q = 0; q < 24; ++q) {
                const float2 v2 = r2[q];
                rmax = fmaxf(rmax, fmaxf(v2.x, v2.y));
            }
            const float thr = rmax + nC5;
            // pass 2: extract up to 8 candidate indices (ascending) + count
            int cnt = 0;
            int c0 = 0, c1 = 0, c2 = 0, c3 = 0, c4 = 0, c5 = 0, c6 = 0, c7 = 0;
#pragma unroll
            for (int q = 0; q < 24; ++q) {
                const float2 v2 = r2[q];
                {
                    const bool tk = (v2.x >= thr); const int e = 2 * q;
                    c0 = (tk && cnt == 0) ? e : c0;  c1 = (tk && cnt == 1) ? e : c1;
                    c2 = (tk && cnt == 2) ? e : c2;  c3 = (tk && cnt == 3) ? e : c3;
                    c4 = (tk && cnt == 4) ? e : c4;  c5 = (tk && cnt == 5) ? e : c5;
                    c6 = (tk && cnt == 6) ? e : c6;  c7 = (tk && cnt == 7) ? e : c7;
                    cnt += tk ? 1 : 0;
                }
                {
                    const bool tk = (v2.y >= thr); const int e = 2 * q + 1;
                    c0 = (tk && cnt == 0) ? e : c0;  c1 = (tk && cnt == 1) ? e : c1;
                    c2 = (tk && cnt == 2) ? e : c2;  c3 = (tk && cnt == 3) ? e : c3;
                    c4 = (tk && cnt == 4) ? e : c4;  c5 = (tk && cnt == 5) ? e : c5;
                    c6 = (tk && cnt == 6) ? e : c6;  c7 = (tk && cnt == 7) ? e : c7;
                    cnt += tk ? 1 : 0;
                }
            }
            // dup-fill (duplicates tie and lose in the encode -> harmless)
            c1 = (cnt >= 2) ? c1 : c0;  c2 = (cnt >= 3) ? c2 : c1;
            c3 = (cnt >= 4) ? c3 : c2;  c4 = (cnt >= 5) ? c4 : c3;
            c5 = (cnt >= 6) ? c5 : c4;  c6 = (cnt >= 7) ? c6 : c5;
            c7 = (cnt >= 8) ? c7 : c6;
            const unsigned cc = (unsigned)(cnt > 15 ? 15 : cnt);
            const unsigned aU = (unsigned)c0 | ((unsigned)c1 << 6) |
                                ((unsigned)c2 << 12) | ((unsigned)c3 << 18) | (cc << 28);
            const unsigned bU = (unsigned)c4 | ((unsigned)c5 << 6) |
                                ((unsigned)c6 << 12) | ((unsigned)c7 << 18);
            const int tt = t0 + tid + 1;                 // mask of row r feeds step r+1
            if (tt < T_DIM) { candA[tt] = aU; candB[tt] = bU; }
            WAVE_SYNC();                                 // before next tile reuses scratch
        }
    }

    // ==== forward recurrence ====
    float ns = potb[jj];                                 // s(0), lane j
    const float* pp = potb + jj;

    float pb[CH];
    unsigned curA[CH], curB[CH];
#pragma unroll
    for (int k = 0; k < CH; ++k) {
        int tt = 1 + k; if (tt > T_DIM - 1) tt = T_DIM - 1;
        pb[k]   = pp[tt * C_DIM];
        curA[k] = candA[tt];
        curB[k] = candB[tt];
    }

    for (int t0 = 1; t0 < L; t0 += CH) {
        float nb[CH]; unsigned nxA[CH], nxB[CH];
#pragma unroll
        for (int k = 0; k < CH; ++k) {                   // prefetch chunk+1
            int tt = t0 + CH + k; if (tt > T_DIM - 1) tt = T_DIM - 1;
            nb[k]  = pp[tt * C_DIM];
            nxA[k] = candA[tt];
            nxB[k] = candB[tt];
        }
#pragma unroll
        for (int k = 0; k < CH; ++k) {
            const int t = t0 + k;
            if (t >= L) break;                           // wave-uniform
            const unsigned aU = (unsigned)__builtin_amdgcn_readfirstlane((int)curA[k]);
            const int cnt = (int)(aU >> 28);
            const int cs0 = (int)(aU & 63u), cs1 = (int)((aU >> 6) & 63u);
            const int cs2 = (int)((aU >> 12) & 63u), cs3 = (int)((aU >> 18) & 63u);
            float mx; int wi;
            if (cnt <= 8) {
                const float s0 = rlane_f(ns, cs0), s1 = rlane_f(ns, cs1);
                const float s2 = rlane_f(ns, cs2), s3 = rlane_f(ns, cs3);
                const float v0 = s0 + trl[cs0 * C_DIM + jj];   // exact ref adds
                const float v1 = s1 + trl[cs1 * C_DIM + jj];
                const float v2 = s2 + trl[cs2 * C_DIM + jj];
                const float v3 = s3 + trl[cs3 * C_DIM + jj];
                if (cnt <= 4) {
                    mx = fmaxf(max3f(v0, v1, v2), v3);
                    // encode: bits(v-mx)|c == c iff v==mx (+0.0), else >=2^31;
                    // min -> lowest max-tier index == first-occurrence argmax.
                    const unsigned u0 = __float_as_uint(v0 - mx) | (unsigned)cs0;
                    const unsigned u1 = __float_as_uint(v1 - mx) | (unsigned)cs1;
                    const unsigned u2 = __float_as_uint(v2 - mx) | (unsigned)cs2;
                    const unsigned u3 = __float_as_uint(v3 - mx) | (unsigned)cs3;
                    wi = (int)umin_(min3u(u0, u1, u2), u3);
                } else {
                    const unsigned bU = (unsigned)__builtin_amdgcn_readfirstlane((int)curB[k]);
                    const int cs4 = (int)(bU & 63u), cs5 = (int)((bU >> 6) & 63u);
                    const int cs6 = (int)((bU >> 12) & 63u), cs7 = (int)((bU >> 18) & 63u);
                    const float s4 = rlane_f(ns, cs4), s5 = rlane_f(ns, cs5);
                    const float s6 = rlane_f(ns, cs6), s7 = rlane_f(ns, cs7);
                    const float v4 = s4 + trl[cs4 * C_DIM + jj];
                    const float v5 = s5 + trl[cs5 * C_DIM + jj];
                    const float v6 = s6 + trl[cs6 * C_DIM + jj];
                    const float v7 = s7 + trl[cs7 * C_DIM + jj];
                    mx = fmaxf(fmaxf(max3f(v0, v1, v2), max3f(v3, v4, v5)), fmaxf(v6, v7));
                    const unsigned u0 = __float_as_uint(v0 - mx) | (unsigned)cs0;
                    const unsigned u1 = __float_as_uint(v1 - mx) | (unsigned)cs1;
                    const unsigned u2 = __float_as_uint(v2 - mx) | (unsigned)cs2;
                    const unsigned u3 = __float_as_uint(v3 - mx) | (unsigned)cs3;
                    const unsigned u4 = __float_as_uint(v4 - mx) | (unsigned)cs4;
                    const unsigned u5 = __float_as_uint(v5 - mx) | (unsigned)cs5;
                    const unsigned u6 = __float_as_uint(v6 - mx) | (unsigned)cs6;
                    const unsigned u7 = __float_as_uint(v7 - mx) | (unsigned)cs7;
                    wi = (int)umin_(umin_(min3u(u0, u1, u2), min3u(u3, u4, u5)),
                                    umin_(u6, u7));
                }
            } else {
                // >8 candidates (~0.1%): exact full serial argmax, ref order.
                mx = rlane_f(ns, 0) + trl[jj]; wi = 0;
#pragma unroll 1
                for (int i = 1; i < C_DIM; ++i) {
                    const float v = rlane_f(ns, i) + trl[i * C_DIM + jj];
                    if (v > mx) { mx = v; wi = i; }      // strict: first occurrence
                }
            }
            // bp store: all 64 lanes; lanes 48-63 spill into row t+1 cols 0-15,
            // overwritten next step (or row thi+1 <= 511: never read).
            bp[t * BPS + tid] = (unsigned char)wi;
            ns = mx + pb[k];                             // exact ref add
        }
#pragma unroll
        for (int k = 0; k < CH; ++k) { pb[k] = nb[k]; curA[k] = nxA[k]; curB[k] = nxB[k]; }
    }

    // publish final scores
    fsc[tid] = ns;
    WAVE_SYNC();
    __syncthreads();   // phase boundary (single wave; cheap)

    // last_tag = argmax over final scores (uniform LDS reads, broadcast)
    const float* fs = fsc;
    float bv = fs[0];
    int   bi = 0;
#pragma unroll
    for (int i = 1; i < C_DIM; ++i) {
        float v = fs[i];
        if (v > bv) { bv = v; bi = i; }
    }
    const int last_tag = __builtin_amdgcn_readfirstlane(bi);

    // prefill tags[t] = last_tag for t in [L, T)
    for (int t = L + tid; t < T_DIM; t += 64) tags[t] = (unsigned char)last_tag;

    // serial backtrace: for t = thi..1: tags[t] = y; y = bp[t][y];  then tags[0] = y
    int y = last_tag;  // wave-uniform
    for (int c0 = (thi >> 6) << 6; c0 >= 0; c0 -= 64) {
        int row[64];   // row[k] holds bp[c0+k][jj] in lane jj
#pragma unroll
        for (int k = 0; k < 64; ++k) row[k] = bp[(c0 + k) * BPS + jj];

        int vacc = 0;
#pragma unroll
        for (int k = 63; k >= 0; --k) {
            const int t = c0 + k;
            vacc = (tid == k) ? y : vacc;                        // tags[t] = y (lane k)
            const int ynew = READLANE_I(row[k], y);
            if ((unsigned)(t - 1) < (unsigned)thi) y = ynew;     // update only t in [1, thi]
        }
        const int tk = c0 + tid;
        if (tk <= thi) tags[tk] = (unsigned char)(vacc & 0xff);
    }
    __syncthreads();   // phase boundary

    // emit one-hot: 4 rows (t) per iteration, 48 lanes x float4 = 768B coalesced
    if (tid < C_DIM) {
        const int r = tid / 12;          // row-in-group 0..3
        const int q = tid - r * 12;      // float4 slot 0..11
        const int cbase = q * 4;
        float* ob = out + (size_t)b * (T_DIM * C_DIM);
        for (int t0 = 0; t0 < T_DIM; t0 += 4) {
            const unsigned int tg4 = *(const unsigned int*)&tags[t0];
            const int mytag = (int)((tg4 >> (r * 8)) & 0xffu);
            float4 v;
            v.x = (cbase + 0 == mytag) ? 1.0f : 0.0f;
            v.y = (cbase + 1 == mytag) ? 1.0f : 0.0f;
            v.z = (cbase + 2 == mytag) ? 1.0f : 0.0f;
            v.w = (cbase + 3 == mytag) ? 1.0f : 0.0f;
            *(float4*)(ob + (size_t)(t0 + r) * C_DIM + cbase) = v;
        }
    }
}

extern "C" void kernel_launch(void* const* d_in, const int* in_sizes, int n_in,
                              void* d_out, int out_size, void* d_ws, size_t ws_size,
                              hipStream_t stream) {
    const float* pot    = (const float*)d_in[0];
    const int*   sl     = (const int*)d_in[1];
    const float* trans  = (const float*)d_in[2];
    float*       out    = (float*)d_out;
    const int B = in_sizes[1];  // sequence_lengths has B elements
    crf_viterbi<<<B, 64, 0, stream>>>(pot, sl, trans, out);
}

// Round 12
// 289.071 us; speedup vs baseline: 1.1218x; 1.1218x over previous
//
#include <hip/hip_runtime.h>

#define T_DIM 512
#define C_DIM 48
#define BPS   48          // bp row stride; 16-lane spill into next row is benign (see store)
#define CH    4           // global-prefetch / pre-phase chunk

#if __has_builtin(__builtin_amdgcn_readlane)
#define READLANE_I(v, l) __builtin_amdgcn_readlane((v), (l))
#else
#define READLANE_I(v, l) __shfl((v), (l), 64)
#endif

// Compiler-level ordering fence for single-wave LDS communication.
#if __has_builtin(__builtin_amdgcn_wave_barrier)
#define WAVE_SYNC() do { __asm__ __volatile__("" ::: "memory"); __builtin_amdgcn_wave_barrier(); } while (0)
#else
#define WAVE_SYNC() __asm__ __volatile__("" ::: "memory")
#endif

__device__ __forceinline__ float rlane_f(float x, int lane) {
    return __int_as_float(READLANE_I(__float_as_int(x), lane));
}

// 4 independent DPP max chains, hand-interleaved so the per-step dependency
// latencies overlap (R11 post-mortem: serial wave_max chains were ~100cy/chunk/row).
__device__ __forceinline__ void wave_max4(float& a, float& b, float& c, float& d) {
#define STEP4(CTRL) do {                                                           \
    int oa = __builtin_amdgcn_update_dpp(__float_as_int(a), __float_as_int(a),     \
                                         (CTRL), 0xF, 0xF, false);                 \
    int ob = __builtin_amdgcn_update_dpp(__float_as_int(b), __float_as_int(b),     \
                                         (CTRL), 0xF, 0xF, false);                 \
    int oc = __builtin_amdgcn_update_dpp(__float_as_int(c), __float_as_int(c),     \
                                         (CTRL), 0xF, 0xF, false);                 \
    int od = __builtin_amdgcn_update_dpp(__float_as_int(d), __float_as_int(d),     \
                                         (CTRL), 0xF, 0xF, false);                 \
    a = fmaxf(a, __int_as_float(oa)); b = fmaxf(b, __int_as_float(ob));            \
    c = fmaxf(c, __int_as_float(oc)); d = fmaxf(d, __int_as_float(od));            \
} while (0)
    STEP4(0x111); STEP4(0x112); STEP4(0x114); STEP4(0x118); STEP4(0x142); STEP4(0x143);
#undef STEP4
    a = __int_as_float(READLANE_I(__float_as_int(a), 63));
    b = __int_as_float(READLANE_I(__float_as_int(b), 63));
    c = __int_as_float(READLANE_I(__float_as_int(c), 63));
    d = __int_as_float(READLANE_I(__float_as_int(d), 63));
}

// single-value wave max (prologue only)
__device__ __forceinline__ float wave_max_f(float v) {
    float x = v, y = v, z = v, w = v;
    wave_max4(x, y, z, w);
    return x;
}

__global__ __launch_bounds__(64) void crf_viterbi(
    const float* __restrict__ pot,     // [B][T][C]
    const int*   __restrict__ seqlen,  // [B][1]
    const float* __restrict__ trans,   // [C][C]
    float*       __restrict__ out)     // [B][T][C] one-hot f32
{
    const int b   = blockIdx.x;
    const int tid = threadIdx.x;
    const int jj  = (tid < C_DIM) ? tid : (C_DIM - 1);  // clamped for safe loads

    __shared__ __align__(16) float trl[C_DIM * C_DIM];   // transitions, row-major
    __shared__ unsigned char bp[T_DIM * BPS];            // rows 1..L-1 used
    __shared__ __align__(4) unsigned char tags[T_DIM];
    __shared__ __align__(16) float fsc[64];              // final scores

    const float* potb = pot + (size_t)b * (T_DIM * C_DIM);
    const int L   = seqlen[b];          // in [1, 511]
    const int thi = L - 1;

    // ---- stage transitions into LDS (coalesced) + tmax = max|Tr| ----
    float tm = 0.0f;
    for (int i = tid; i < C_DIM * C_DIM; i += 64) {      // 36 iters exactly
        float v = trans[i];
        trl[i] = v;
        tm = fmaxf(tm, fabsf(v));
    }
    const float tmax = wave_max_f(tm);                   // uniform
    // Window: true winner i* for any column satisfies pot_i* >= pmax - 4*tmax
    // (|m_i - m_j| <= 2tmax and win-condition 2tmax; R10/R11 derivation).
    // fl-rounding slack needed <= ~7e-4 at |s|<=2500; 1e-3 margin covers it.
    const float nC4 = -(4.0f * tmax + 1e-3f);
    WAVE_SYNC();                                         // trl visible (same wave)

    // ---- init: lane j holds s(0)[j]; prow = pot row t-1 for mask building ----
    float ns   = potb[jj];
    float prow = ns;

    const float* pp = potb + jj;

    float pb[CH];
#pragma unroll
    for (int k = 0; k < CH; ++k) {
        int tt = 1 + k; if (tt > T_DIM - 1) tt = T_DIM - 1;
        pb[k] = pp[tt * C_DIM];
    }

    for (int t0 = 1; t0 < L; t0 += CH) {
        // ---- global prefetch for chunk+1 ----
        float nb[CH];
#pragma unroll
        for (int k = 0; k < CH; ++k) {
            int tt = t0 + CH + k; if (tt > T_DIM - 1) tt = T_DIM - 1;
            nb[k] = pp[tt * C_DIM];
        }

        // ==== pre-phase (input-only, off the recurrence chain) ====
        // rows feeding masks for steps t0..t0+3 are t0-1..t0+2:
        float r0 = prow, r1 = pb[0], r2 = pb[1], r3 = pb[2];
        float p0 = r0, p1 = r1, p2 = r2, p3 = r3;
        wave_max4(p0, p1, p2, p3);                       // pmax per row, uniform
        unsigned long long mk[CH];
        mk[0] = __ballot(r0 >= p0 + nC4) & 0x0000FFFFFFFFFFFFull;
        mk[1] = __ballot(r1 >= p1 + nC4) & 0x0000FFFFFFFFFFFFull;
        mk[2] = __ballot(r2 >= p2 + nC4) & 0x0000FFFFFFFFFFFFull;
        mk[3] = __ballot(r3 >= p3 + nC4) & 0x0000FFFFFFFFFFFFull;
        int ca[CH], cb[CH], cc[CH], cd[CH];
        bool h3[CH];
        unsigned long long rest[CH];
        float ga[CH], gb[CH], gc[CH], gd[CH];
#pragma unroll
        for (int k = 0; k < CH; ++k) {
            unsigned long long mm = mk[k];
            if (!mm) mm = 0x0000FFFFFFFFFFFFull;         // defensive (provably non-empty)
            const int c0 = (int)__builtin_ctzll(mm);
            const unsigned long long m1 = mm & (mm - 1);
            const int c1 = m1 ? (int)__builtin_ctzll(m1) : c0;
            const unsigned long long m2 = m1 & (m1 - 1);
            const int c2 = m2 ? (int)__builtin_ctzll(m2) : c1;
            const unsigned long long m3 = m2 & (m2 - 1);
            const int c3 = m3 ? (int)__builtin_ctzll(m3) : c2;
            ca[k] = c0; cb[k] = c1; cc[k] = c2; cd[k] = c3;
            h3[k] = (m2 != 0);
            rest[k] = m3 & (m3 - 1);
            // candidate transition values, batched LDS (one wait, off-chain):
            ga[k] = trl[c0 * C_DIM + jj];
            gb[k] = trl[c1 * C_DIM + jj];
            gc[k] = trl[c2 * C_DIM + jj];
            gd[k] = trl[c3 * C_DIM + jj];
        }

        // ==== serial recurrence: readlane -> add -> select -> ns ====
#pragma unroll
        for (int k = 0; k < CH; ++k) {
            const int t = t0 + k;
            if (t >= L) break;                           // wave-uniform
            const float sa = rlane_f(ns, ca[k]);
            const float sb = rlane_f(ns, cb[k]);
            const float va = sa + ga[k];                 // exact ref adds
            const float vb = sb + gb[k];
            // ascending-index strict-> == first-occurrence; dup-pad ties lose.
            float mx = va; int wi = ca[k];
            if (vb > va) { mx = vb; wi = cb[k]; }
            if (h3[k]) {                                 // uniform branch, P ~ 0.2
                const float sc_ = rlane_f(ns, cc[k]);
                const float sd_ = rlane_f(ns, cd[k]);
                const float vc = sc_ + gc[k];
                const float vd = sd_ + gd[k];
                if (vc > mx) { mx = vc; wi = cc[k]; }
                if (vd > mx) { mx = vd; wi = cd[k]; }
            }
            unsigned long long rr = rest[k];
            while (rr) {                                 // rare (>4 candidates)
                int c = (int)__builtin_ctzll(rr); rr &= rr - 1;
                float s = rlane_f(ns, c);
                float cv = s + trl[c * C_DIM + jj];
                if (cv > mx) { mx = cv; wi = c; }        // strict: first occurrence
            }
            // bp store: all 64 lanes; lanes 48-63 spill into row t+1 cols 0-15,
            // overwritten next step (or row thi+1 <= 511: never read).
            bp[t * BPS + tid] = (unsigned char)wi;
            ns = mx + pb[k];                             // exact ref add
        }
        prow = pb[CH - 1];
#pragma unroll
        for (int k = 0; k < CH; ++k) pb[k] = nb[k];
    }

    // publish final scores
    fsc[tid] = ns;
    WAVE_SYNC();
    __syncthreads();   // phase boundary (single wave; cheap)

    // last_tag = argmax over final scores (uniform LDS reads, broadcast)
    const float* fs = fsc;
    float bv = fs[0];
    int   bi = 0;
#pragma unroll
    for (int i = 1; i < C_DIM; ++i) {
        float v = fs[i];
        if (v > bv) { bv = v; bi = i; }
    }
    const int last_tag = __builtin_amdgcn_readfirstlane(bi);

    // prefill tags[t] = last_tag for t in [L, T)
    for (int t = L + tid; t < T_DIM; t += 64) tags[t] = (unsigned char)last_tag;

    // serial backtrace: for t = thi..1: tags[t] = y; y = bp[t][y];  then tags[0] = y
    int y = last_tag;  // wave-uniform
    for (int c0 = (thi >> 6) << 6; c0 >= 0; c0 -= 64) {
        int row[64];   // row[k] holds bp[c0+k][jj] in lane jj
#pragma unroll
        for (int k = 0; k < 64; ++k) row[k] = bp[(c0 + k) * BPS + jj];

        int vacc = 0;
#pragma unroll
        for (int k = 63; k >= 0; --k) {
            const int t = c0 + k;
            vacc = (tid == k) ? y : vacc;                        // tags[t] = y (lane k)
            const int ynew = READLANE_I(row[k], y);
            if ((unsigned)(t - 1) < (unsigned)thi) y = ynew;     // update only t in [1, thi]
        }
        const int tk = c0 + tid;
        if (tk <= thi) tags[tk] = (unsigned char)(vacc & 0xff);
    }
    __syncthreads();   // phase boundary

    // emit one-hot: 4 rows (t) per iteration, 48 lanes x float4 = 768B coalesced
    if (tid < C_DIM) {
        const int r = tid / 12;          // row-in-group 0..3
        const int q = tid - r * 12;      // float4 slot 0..11
        const int cbase = q * 4;
        float* ob = out + (size_t)b * (T_DIM * C_DIM);
        for (int t0 = 0; t0 < T_DIM; t0 += 4) {
            const unsigned int tg4 = *(const unsigned int*)&tags[t0];
            const int mytag = (int)((tg4 >> (r * 8)) & 0xffu);
            float4 v;
            v.x = (cbase + 0 == mytag) ? 1.0f : 0.0f;
            v.y = (cbase + 1 == mytag) ? 1.0f : 0.0f;
            v.z = (cbase + 2 == mytag) ? 1.0f : 0.0f;
            v.w = (cbase + 3 == mytag) ? 1.0f : 0.0f;
            *(float4*)(ob + (size_t)(t0 + r) * C_DIM + cbase) = v;
        }
    }
}

extern "C" void kernel_launch(void* const* d_in, const int* in_sizes, int n_in,
                              void* d_out, int out_size, void* d_ws, size_t ws_size,
                              hipStream_t stream) {
    const float* pot    = (const float*)d_in[0];
    const int*   sl     = (const int*)d_in[1];
    const float* trans  = (const float*)d_in[2];
    float*       out    = (float*)d_out;
    const int B = in_sizes[1];  // sequence_lengths has B elements
    crf_viterbi<<<B, 64, 0, stream>>>(pot, sl, trans, out);
}